// Round 1
// baseline (202.253 us; speedup 1.0000x reference)
//
#include <hip/hip_runtime.h>
#include <hip/hip_bf16.h>
#include <stdint.h>

// Problem constants (from reference): N=16384, K=2048, D=512
#define NN 16384
#define KK 2048
#define DD 512

typedef __bf16 bf16x8 __attribute__((ext_vector_type(8)));
typedef float f32x4 __attribute__((ext_vector_type(4)));
typedef unsigned short ushort_t;
typedef ushort_t us8 __attribute__((ext_vector_type(8)));

#define AS1(p) ((const __attribute__((address_space(1))) void*)(p))
#define AS3(p) ((__attribute__((address_space(3))) void*)(p))

__device__ inline ushort_t f2bf(float f) {
  uint32_t u = __float_as_uint(f);
  u += 0x7fffu + ((u >> 16) & 1u);   // RNE
  return (ushort_t)(u >> 16);
}

// ---- Kernel 1: convert x rows to bf16, compute x_sq[n] = sum(x^2) ----
__global__ __launch_bounds__(256) void prep_x(const float* __restrict__ x,
                                              ushort_t* __restrict__ xb,
                                              float* __restrict__ x_sq) {
  const int wave = threadIdx.x >> 6;
  const int lane = threadIdx.x & 63;
  const int row = blockIdx.x * 4 + wave;
  const float* xr = x + (size_t)row * DD + lane * 8;
  float4 v0 = *reinterpret_cast<const float4*>(xr);
  float4 v1 = *reinterpret_cast<const float4*>(xr + 4);
  float s = v0.x*v0.x + v0.y*v0.y + v0.z*v0.z + v0.w*v0.w
          + v1.x*v1.x + v1.y*v1.y + v1.z*v1.z + v1.w*v1.w;
  us8 o;
  o[0]=f2bf(v0.x); o[1]=f2bf(v0.y); o[2]=f2bf(v0.z); o[3]=f2bf(v0.w);
  o[4]=f2bf(v1.x); o[5]=f2bf(v1.y); o[6]=f2bf(v1.z); o[7]=f2bf(v1.w);
  *reinterpret_cast<us8*>(xb + (size_t)row * DD + lane * 8) = o;
  #pragma unroll
  for (int off = 32; off; off >>= 1) s += __shfl_xor(s, off, 64);
  if (lane == 0) x_sq[row] = s;
}

// ---- Kernel 2: convert mu rows to bf16, fold mu_sq/denom/log into per-k consts ----
__global__ __launch_bounds__(256) void prep_mu(const float* __restrict__ mu,
                                               const float* __restrict__ sd,
                                               ushort_t* __restrict__ mub,
                                               float* __restrict__ inv_denom,
                                               float* __restrict__ beta) {
  const int wave = threadIdx.x >> 6;
  const int lane = threadIdx.x & 63;
  const int row = blockIdx.x * 4 + wave;
  const float* mr = mu + (size_t)row * DD + lane * 8;
  float4 v0 = *reinterpret_cast<const float4*>(mr);
  float4 v1 = *reinterpret_cast<const float4*>(mr + 4);
  float musq = v0.x*v0.x + v0.y*v0.y + v0.z*v0.z + v0.w*v0.w
             + v1.x*v1.x + v1.y*v1.y + v1.z*v1.z + v1.w*v1.w;
  us8 o;
  o[0]=f2bf(v0.x); o[1]=f2bf(v0.y); o[2]=f2bf(v0.z); o[3]=f2bf(v0.w);
  o[4]=f2bf(v1.x); o[5]=f2bf(v1.y); o[6]=f2bf(v1.z); o[7]=f2bf(v1.w);
  *reinterpret_cast<us8*>(mub + (size_t)row * DD + lane * 8) = o;

  const float* sr = sd + (size_t)row * DD + lane * 8;
  float4 s0 = *reinterpret_cast<const float4*>(sr);
  float4 s1 = *reinterpret_cast<const float4*>(sr + 4);
  float ssum = s0.x + s0.y + s0.z + s0.w + s1.x + s1.y + s1.z + s1.w;
  float ssq  = s0.x*s0.x + s0.y*s0.y + s0.z*s0.z + s0.w*s0.w
             + s1.x*s1.x + s1.y*s1.y + s1.z*s1.z + s1.w*s1.w;
  #pragma unroll
  for (int off = 32; off; off >>= 1) {
    musq += __shfl_xor(musq, off, 64);
    ssum += __shfl_xor(ssum, off, 64);
    ssq  += __shfl_xor(ssq,  off, 64);
  }
  if (lane == 0) {
    float idn = 1.0f / (2.0f * ssq + 1e-8f);
    inv_denom[row] = idn;
    beta[row] = musq * idn + logf(ssum) + 0.91893853320467274f; // +0.5*log(2*pi)
  }
}

// ---- Kernel 3: 128x128-tile bf16 MFMA GEMM with fused affine epilogue ----
// out[n][k] = (2*dot(x_n, mu_k) - x_sq[n]) * inv_denom[k] - beta[k]
__global__ __launch_bounds__(256) void gemm_eval(const ushort_t* __restrict__ xb,
                                                 const ushort_t* __restrict__ mub,
                                                 const float* __restrict__ x_sq,
                                                 const float* __restrict__ inv_denom,
                                                 const float* __restrict__ beta,
                                                 float* __restrict__ out) {
  __shared__ __align__(16) ushort_t As[128 * 32];  // [row][k] linear, 8KB
  __shared__ __align__(16) ushort_t Bs[128 * 32];

  const int t = threadIdx.x;
  const int lane = t & 63;
  const int w = t >> 6;          // wave 0..3
  const int wrow = w >> 1;       // 2x2 wave grid, each wave 64x64
  const int wcol = w & 1;

  const int bm = blockIdx.x >> 4;      // 128 row-tiles
  const int bn = blockIdx.x & 15;      // 16 col-tiles
  const int brow = bm * 128;
  const int bcol = bn * 128;

  f32x4 acc[4][4];
  #pragma unroll
  for (int m = 0; m < 4; ++m)
    #pragma unroll
    for (int c = 0; c < 4; ++c)
      acc[m][c] = (f32x4){0.f, 0.f, 0.f, 0.f};

  const int c0 = t;         // staging chunk ids (16B chunks), 512 per tile
  const int c1 = t + 256;

  const int rl = lane & 15;
  const int slot = lane >> 4;

  for (int kt = 0; kt < DD / 32; ++kt) {
    const int kb = kt * 32;
    // stage A tile (128x32 bf16) and B tile via global_load_lds, 16B/lane
    {
      const ushort_t* g0 = xb + (size_t)(brow + (c0 >> 2)) * DD + kb + (c0 & 3) * 8;
      __builtin_amdgcn_global_load_lds(AS1(g0), AS3(As + c0 * 8), 16, 0, 0);
      const ushort_t* g1 = xb + (size_t)(brow + (c1 >> 2)) * DD + kb + (c1 & 3) * 8;
      __builtin_amdgcn_global_load_lds(AS1(g1), AS3(As + c1 * 8), 16, 0, 0);
      const ushort_t* h0 = mub + (size_t)(bcol + (c0 >> 2)) * DD + kb + (c0 & 3) * 8;
      __builtin_amdgcn_global_load_lds(AS1(h0), AS3(Bs + c0 * 8), 16, 0, 0);
      const ushort_t* h1 = mub + (size_t)(bcol + (c1 >> 2)) * DD + kb + (c1 & 3) * 8;
      __builtin_amdgcn_global_load_lds(AS1(h1), AS3(Bs + c1 * 8), 16, 0, 0);
    }
    __syncthreads();   // drains vmcnt before barrier

    const bf16x8* A8 = reinterpret_cast<const bf16x8*>(As);
    const bf16x8* B8 = reinterpret_cast<const bf16x8*>(Bs);
    bf16x8 af[4], bfr[4];
    #pragma unroll
    for (int m = 0; m < 4; ++m)
      af[m] = A8[(wrow * 64 + m * 16 + rl) * 4 + slot];
    #pragma unroll
    for (int c = 0; c < 4; ++c)
      bfr[c] = B8[(wcol * 64 + c * 16 + rl) * 4 + slot];

    #pragma unroll
    for (int m = 0; m < 4; ++m)
      #pragma unroll
      for (int c = 0; c < 4; ++c)
        acc[m][c] = __builtin_amdgcn_mfma_f32_16x16x32_bf16(af[m], bfr[c], acc[m][c], 0, 0, 0);

    __syncthreads();   // protect LDS before next stage
  }

  // epilogue: C/D layout col=lane&15, row=(lane>>4)*4+reg  [m89-verified]
  const int rh = lane >> 4;
  float inv[4], bet[4];
  #pragma unroll
  for (int c = 0; c < 4; ++c) {
    int k = bcol + wcol * 64 + c * 16 + rl;
    inv[c] = inv_denom[k];
    bet[c] = beta[k];
  }
  #pragma unroll
  for (int m = 0; m < 4; ++m) {
    #pragma unroll
    for (int r = 0; r < 4; ++r) {
      int n = brow + wrow * 64 + m * 16 + rh * 4 + r;
      float xs = x_sq[n];
      size_t base = (size_t)n * KK + bcol + wcol * 64;
      #pragma unroll
      for (int c = 0; c < 4; ++c) {
        out[base + c * 16 + rl] = (2.0f * acc[m][c][r] - xs) * inv[c] - bet[c];
      }
    }
  }
}

extern "C" void kernel_launch(void* const* d_in, const int* in_sizes, int n_in,
                              void* d_out, int out_size, void* d_ws, size_t ws_size,
                              hipStream_t stream) {
  const float* x   = (const float*)d_in[0];
  const float* mu  = (const float*)d_in[1];
  const float* sd  = (const float*)d_in[2];
  float* out = (float*)d_out;

  char* ws = (char*)d_ws;
  ushort_t* xb        = (ushort_t*)(ws);                    // N*D*2   = 16777216 B
  ushort_t* mub       = (ushort_t*)(ws + 16777216);         // K*D*2   =  2097152 B
  float*    x_sq      = (float*)(ws + 18874368);            // N*4     =    65536 B
  float*    inv_denom = (float*)(ws + 18939904);            // K*4
  float*    beta      = (float*)(ws + 18948096);            // K*4

  prep_x<<<NN / 4, 256, 0, stream>>>(x, xb, x_sq);
  prep_mu<<<KK / 4, 256, 0, stream>>>(mu, sd, mub, inv_denom, beta);
  gemm_eval<<<(NN / 128) * (KK / 128), 256, 0, stream>>>(xb, mub, x_sq, inv_denom, beta, out);
}

// Round 2
// 202.222 us; speedup vs baseline: 1.0002x; 1.0002x over previous
//
#include <hip/hip_runtime.h>
#include <hip/hip_bf16.h>
#include <stdint.h>

// Problem constants: N=16384, K=2048, D=512
#define NN 16384
#define KK 2048
#define DD 512

typedef __bf16 bf16x8 __attribute__((ext_vector_type(8)));
typedef float f32x4 __attribute__((ext_vector_type(4)));
typedef unsigned short ushort_t;
typedef ushort_t us8 __attribute__((ext_vector_type(8)));

#define AS1(p) ((const __attribute__((address_space(1))) void*)(p))
#define AS3(p) ((__attribute__((address_space(3))) void*)(p))

#define FENCE() asm volatile("" ::: "memory")
#define SBAR()  do { FENCE(); __builtin_amdgcn_s_barrier(); FENCE(); } while (0)
#define WAITVM0() asm volatile("s_waitcnt vmcnt(0)" ::: "memory")

__device__ inline ushort_t f2bf(float f) {
  uint32_t u = __float_as_uint(f);
  u += 0x7fffu + ((u >> 16) & 1u);   // RNE
  return (ushort_t)(u >> 16);
}

// ---------------------------------------------------------------------------
// Packed "tile image" layout (per 256-row x 64-k K-tile, 16384 bf16 = 32KB):
//   element (rowLocal = m*16 + r, kLocal = ks*32 + slot*8 + j), m in 0..15,
//   ks in 0..1, slot in 0..3, r in 0..15, j in 0..7:
//     elem = (m*2 + ks)*512 + slot*128 + r*8 + j
//   i.e. [m][ks][lane = slot*16 + r][j] -- exactly the mfma_16x16x32 A/B
//   fragment order, so LDS reads are lane-linear ds_read_b128 (conflict-free)
//   and global->LDS staging is a linear 32KB memcpy via global_load_lds.
// xb image index:  (br*8 + kt)   br = n>>8,   64 row-blocks
// mub image index: (bc*8 + kt)   bc = k>>8,   8 col-blocks
// ---------------------------------------------------------------------------

// ---- Kernel 1: x -> packed bf16 images + x_sq[n] ----
__global__ __launch_bounds__(256) void prep_x(const float* __restrict__ x,
                                              ushort_t* __restrict__ xb,
                                              float* __restrict__ x_sq) {
  const int wave = threadIdx.x >> 6;
  const int lane = threadIdx.x & 63;
  const int row = blockIdx.x * 4 + wave;
  const float* xr = x + (size_t)row * DD + lane * 8;
  float4 v0 = *reinterpret_cast<const float4*>(xr);
  float4 v1 = *reinterpret_cast<const float4*>(xr + 4);
  float s = v0.x*v0.x + v0.y*v0.y + v0.z*v0.z + v0.w*v0.w
          + v1.x*v1.x + v1.y*v1.y + v1.z*v1.z + v1.w*v1.w;
  us8 o;
  o[0]=f2bf(v0.x); o[1]=f2bf(v0.y); o[2]=f2bf(v0.z); o[3]=f2bf(v0.w);
  o[4]=f2bf(v1.x); o[5]=f2bf(v1.y); o[6]=f2bf(v1.z); o[7]=f2bf(v1.w);

  const int br = row >> 8, m = (row >> 4) & 15, r = row & 15;
  const int kt = lane >> 3, cc2 = lane & 7, ks = cc2 >> 2, slot = cc2 & 3;
  size_t off = (size_t)(br * 8 + kt) * 16384 + (m * 2 + ks) * 512 + slot * 128 + r * 8;
  *reinterpret_cast<us8*>(xb + off) = o;

  #pragma unroll
  for (int offs = 32; offs; offs >>= 1) s += __shfl_xor(s, offs, 64);
  if (lane == 0) x_sq[row] = s;
}

// ---- Kernel 2: mu -> packed bf16 images + per-k constants ----
__global__ __launch_bounds__(256) void prep_mu(const float* __restrict__ mu,
                                               const float* __restrict__ sd,
                                               ushort_t* __restrict__ mub,
                                               float* __restrict__ inv_denom,
                                               float* __restrict__ beta) {
  const int wave = threadIdx.x >> 6;
  const int lane = threadIdx.x & 63;
  const int row = blockIdx.x * 4 + wave;
  const float* mr = mu + (size_t)row * DD + lane * 8;
  float4 v0 = *reinterpret_cast<const float4*>(mr);
  float4 v1 = *reinterpret_cast<const float4*>(mr + 4);
  float musq = v0.x*v0.x + v0.y*v0.y + v0.z*v0.z + v0.w*v0.w
             + v1.x*v1.x + v1.y*v1.y + v1.z*v1.z + v1.w*v1.w;
  us8 o;
  o[0]=f2bf(v0.x); o[1]=f2bf(v0.y); o[2]=f2bf(v0.z); o[3]=f2bf(v0.w);
  o[4]=f2bf(v1.x); o[5]=f2bf(v1.y); o[6]=f2bf(v1.z); o[7]=f2bf(v1.w);

  const int bc = row >> 8, cB = (row >> 4) & 15, r = row & 15;
  const int kt = lane >> 3, cc2 = lane & 7, ks = cc2 >> 2, slot = cc2 & 3;
  size_t off = (size_t)(bc * 8 + kt) * 16384 + (cB * 2 + ks) * 512 + slot * 128 + r * 8;
  *reinterpret_cast<us8*>(mub + off) = o;

  const float* sr = sd + (size_t)row * DD + lane * 8;
  float4 s0 = *reinterpret_cast<const float4*>(sr);
  float4 s1 = *reinterpret_cast<const float4*>(sr + 4);
  float ssum = s0.x + s0.y + s0.z + s0.w + s1.x + s1.y + s1.z + s1.w;
  float ssq  = s0.x*s0.x + s0.y*s0.y + s0.z*s0.z + s0.w*s0.w
             + s1.x*s1.x + s1.y*s1.y + s1.z*s1.z + s1.w*s1.w;
  #pragma unroll
  for (int offs = 32; offs; offs >>= 1) {
    musq += __shfl_xor(musq, offs, 64);
    ssum += __shfl_xor(ssum, offs, 64);
    ssq  += __shfl_xor(ssq,  offs, 64);
  }
  if (lane == 0) {
    float idn = 1.0f / (2.0f * ssq + 1e-8f);
    inv_denom[row] = idn;
    beta[row] = musq * idn + logf(ssum) + 0.91893853320467274f; // + 0.5*log(2pi)
  }
}

// ---- Kernel 3: 256x256-tile, BK=64, 8-wave, 4-phase/K-tile MFMA GEMM ----
// out[n][k] = (2*dot - x_sq[n]) * inv_denom[k] - beta[k]
__global__ __launch_bounds__(512, 2) void gemm_eval(const ushort_t* __restrict__ xb,
                                                    const ushort_t* __restrict__ mub,
                                                    const float* __restrict__ x_sq,
                                                    const float* __restrict__ inv_denom,
                                                    const float* __restrict__ beta,
                                                    float* __restrict__ out) {
  __shared__ __align__(16) ushort_t As[2][16384];  // 2 x 32KB
  __shared__ __align__(16) ushort_t Bs[2][16384];  // 2 x 32KB  -> 128KB total

  const int t0 = threadIdx.x;
  const int lane = t0 & 63;
  const int w = t0 >> 6;
  const int wrow = w >> 2;   // 0..1  (128-row half)
  const int wcol = w & 3;    // 0..3  (64-col quarter)

  // bijective XCD swizzle: grid 512 = 64 bm x 8 bn, 512 % 8 == 0
  const int bid = blockIdx.x;
  const int swz = (bid & 7) * 64 + (bid >> 3);
  const int bm = swz >> 3, bn = swz & 7;   // each XCD: 8 consecutive bm x all bn

  const ushort_t* Ag = xb  + (size_t)bm * (8 * 16384);
  const ushort_t* Bg = mub + (size_t)bn * (8 * 16384);

  f32x4 acc[8][4];
  #pragma unroll
  for (int mmi = 0; mmi < 8; ++mmi)
    #pragma unroll
    for (int cc = 0; cc < 4; ++cc)
      acc[mmi][cc] = (f32x4){0.f, 0.f, 0.f, 0.f};

  // linear 32KB+32KB copy, 8 x global_load_lds(16B) per thread
#define STAGE(kt, dbuf) do {                                                        \
    const ushort_t* as_ = Ag + (size_t)(kt) * 16384;                                \
    const ushort_t* bs_ = Bg + (size_t)(kt) * 16384;                                \
    ushort_t* ad_ = &As[dbuf][0];                                                   \
    ushort_t* bd_ = &Bs[dbuf][0];                                                   \
    __builtin_amdgcn_global_load_lds(AS1(as_ + t0*8),        AS3(ad_ + t0*8),        16, 0, 0); \
    __builtin_amdgcn_global_load_lds(AS1(as_ + (t0+512)*8),  AS3(ad_ + (t0+512)*8),  16, 0, 0); \
    __builtin_amdgcn_global_load_lds(AS1(as_ + (t0+1024)*8), AS3(ad_ + (t0+1024)*8), 16, 0, 0); \
    __builtin_amdgcn_global_load_lds(AS1(as_ + (t0+1536)*8), AS3(ad_ + (t0+1536)*8), 16, 0, 0); \
    __builtin_amdgcn_global_load_lds(AS1(bs_ + t0*8),        AS3(bd_ + t0*8),        16, 0, 0); \
    __builtin_amdgcn_global_load_lds(AS1(bs_ + (t0+512)*8),  AS3(bd_ + (t0+512)*8),  16, 0, 0); \
    __builtin_amdgcn_global_load_lds(AS1(bs_ + (t0+1024)*8), AS3(bd_ + (t0+1024)*8), 16, 0, 0); \
    __builtin_amdgcn_global_load_lds(AS1(bs_ + (t0+1536)*8), AS3(bd_ + (t0+1536)*8), 16, 0, 0); \
  } while (0)

  // prologue: stage K-tile 0
  STAGE(0, 0);
  WAITVM0();
  SBAR();

  for (int t = 0; t < 8; ++t) {           // 8 K-tiles of 64
    const ushort_t* Acur = &As[t & 1][0];
    const ushort_t* Bcur = &Bs[t & 1][0];
    bf16x8 bfrag[4][2];
    #pragma unroll
    for (int q = 0; q < 4; ++q) {         // 4 phases, 16 MFMA each
      bf16x8 af[2][2];
      #pragma unroll
      for (int i = 0; i < 2; ++i)
        #pragma unroll
        for (int ks = 0; ks < 2; ++ks)
          af[i][ks] = *reinterpret_cast<const bf16x8*>(
              Acur + ((wrow * 8 + q * 2 + i) * 2 + ks) * 512 + lane * 8);
      if (q == 0) {
        #pragma unroll
        for (int cc = 0; cc < 4; ++cc)
          #pragma unroll
          for (int ks = 0; ks < 2; ++ks)
            bfrag[cc][ks] = *reinterpret_cast<const bf16x8*>(
                Bcur + ((wcol * 4 + cc) * 2 + ks) * 512 + lane * 8);
        if (t < 7) STAGE(t + 1, (t + 1) & 1);   // prefetch stays in flight ~3 phases
      }
      SBAR();
      __builtin_amdgcn_s_setprio(1);
      #pragma unroll
      for (int i = 0; i < 2; ++i)
        #pragma unroll
        for (int cc = 0; cc < 4; ++cc)
          #pragma unroll
          for (int ks = 0; ks < 2; ++ks)
            acc[q * 2 + i][cc] = __builtin_amdgcn_mfma_f32_16x16x32_bf16(
                af[i][ks], bfrag[cc][ks], acc[q * 2 + i][cc], 0, 0, 0);
      __builtin_amdgcn_s_setprio(0);
      if (q == 3) WAITVM0();               // the ONLY vmem drain, once per K-tile
      SBAR();
    }
  }

  // epilogue: C/D layout col=lane&15, row=(lane>>4)*4+reg  [verified round 0]
  const int rl = lane & 15, rh = lane >> 4;
  const int colbase = bn * 256 + wcol * 64;
  float inv[4], bet[4];
  #pragma unroll
  for (int cc = 0; cc < 4; ++cc) {
    inv[cc] = inv_denom[colbase + cc * 16 + rl];
    bet[cc] = beta[colbase + cc * 16 + rl];
  }
  #pragma unroll
  for (int mmi = 0; mmi < 8; ++mmi) {
    const int nb = bm * 256 + wrow * 128 + mmi * 16 + rh * 4;
    #pragma unroll
    for (int reg = 0; reg < 4; ++reg) {
      const int n = nb + reg;
      const float xs = x_sq[n];
      float* op = out + (size_t)n * KK + colbase;
      #pragma unroll
      for (int cc = 0; cc < 4; ++cc)
        op[cc * 16 + rl] = (2.0f * acc[mmi][cc][reg] - xs) * inv[cc] - bet[cc];
    }
  }
#undef STAGE
}

extern "C" void kernel_launch(void* const* d_in, const int* in_sizes, int n_in,
                              void* d_out, int out_size, void* d_ws, size_t ws_size,
                              hipStream_t stream) {
  const float* x   = (const float*)d_in[0];
  const float* mu  = (const float*)d_in[1];
  const float* sd  = (const float*)d_in[2];
  float* out = (float*)d_out;

  char* ws = (char*)d_ws;
  ushort_t* xb        = (ushort_t*)(ws);                    // N*D*2 = 16777216 B
  ushort_t* mub       = (ushort_t*)(ws + 16777216);         // K*D*2 =  2097152 B
  float*    x_sq      = (float*)(ws + 18874368);            // N*4
  float*    inv_denom = (float*)(ws + 18939904);            // K*4
  float*    beta      = (float*)(ws + 18948096);            // K*4

  prep_x<<<NN / 4, 256, 0, stream>>>(x, xb, x_sq);
  prep_mu<<<KK / 4, 256, 0, stream>>>(mu, sd, mub, inv_denom, beta);
  gemm_eval<<<(NN / 256) * (KK / 256), 512, 0, stream>>>(xb, mub, x_sq, inv_denom, beta, out);
}

// Round 3
// 199.284 us; speedup vs baseline: 1.0149x; 1.0147x over previous
//
#include <hip/hip_runtime.h>
#include <hip/hip_bf16.h>
#include <stdint.h>

// Problem constants: N=16384, K=2048, D=512
#define NN 16384
#define KK 2048
#define DD 512

typedef __bf16 bf16x8 __attribute__((ext_vector_type(8)));
typedef float f32x4 __attribute__((ext_vector_type(4)));
typedef unsigned short ushort_t;
typedef ushort_t us8 __attribute__((ext_vector_type(8)));

#define AS1(p) ((const __attribute__((address_space(1))) void*)(p))
#define AS3(p) ((__attribute__((address_space(3))) void*)(p))
#define FENCE() asm volatile("" ::: "memory")
#define SBAR()  do { FENCE(); __builtin_amdgcn_s_barrier(); FENCE(); } while (0)

__device__ inline ushort_t f2bf(float f) {
  uint32_t u = __float_as_uint(f);
  u += 0x7fffu + ((u >> 16) & 1u);   // RNE
  return (ushort_t)(u >> 16);
}

// ---------------------------------------------------------------------------
// Packed fragment-major images, BK=32 granularity.
// One image = 128 rows x 32 k = 4096 bf16 = 8KB, laid out so that the MFMA
// A/B fragment read for m-block m is a lane-linear ds_read_b128:
//   elem(row = m*16 + r, k = slot*8 + j) -> m*512 + slot*128 + r*8 + j
//   (read side: frag addr = m*512 + lane*8, lane = slot*16 + r)
// xb image id  = (br*16 + kt), br = row>>7 (128 row-blocks), kt = k>>5 (16)
// mub image id = (bc*16 + kt), bc = col>>7 (16 col-blocks)
// ---------------------------------------------------------------------------

// ---- Kernel 1: x -> packed bf16 images + x_sq[n] ----
__global__ __launch_bounds__(256) void prep_x(const float* __restrict__ x,
                                              ushort_t* __restrict__ xb,
                                              float* __restrict__ x_sq) {
  const int wave = threadIdx.x >> 6;
  const int lane = threadIdx.x & 63;
  const int row = blockIdx.x * 4 + wave;
  const float* xr = x + (size_t)row * DD + lane * 8;
  float4 v0 = *reinterpret_cast<const float4*>(xr);
  float4 v1 = *reinterpret_cast<const float4*>(xr + 4);
  float s = v0.x*v0.x + v0.y*v0.y + v0.z*v0.z + v0.w*v0.w
          + v1.x*v1.x + v1.y*v1.y + v1.z*v1.z + v1.w*v1.w;
  us8 o;
  o[0]=f2bf(v0.x); o[1]=f2bf(v0.y); o[2]=f2bf(v0.z); o[3]=f2bf(v0.w);
  o[4]=f2bf(v1.x); o[5]=f2bf(v1.y); o[6]=f2bf(v1.z); o[7]=f2bf(v1.w);

  const int br = row >> 7, m = (row >> 4) & 7, r = row & 15;
  const int kt = lane >> 2, slot = lane & 3;
  size_t off = ((size_t)(br * 16 + kt)) * 4096 + m * 512 + slot * 128 + r * 8;
  *reinterpret_cast<us8*>(xb + off) = o;

  #pragma unroll
  for (int offs = 32; offs; offs >>= 1) s += __shfl_xor(s, offs, 64);
  if (lane == 0) x_sq[row] = s;
}

// ---- Kernel 2: mu -> packed bf16 images + per-k constants ----
__global__ __launch_bounds__(256) void prep_mu(const float* __restrict__ mu,
                                               const float* __restrict__ sd,
                                               ushort_t* __restrict__ mub,
                                               float* __restrict__ inv_denom,
                                               float* __restrict__ beta) {
  const int wave = threadIdx.x >> 6;
  const int lane = threadIdx.x & 63;
  const int row = blockIdx.x * 4 + wave;
  const float* mr = mu + (size_t)row * DD + lane * 8;
  float4 v0 = *reinterpret_cast<const float4*>(mr);
  float4 v1 = *reinterpret_cast<const float4*>(mr + 4);
  float musq = v0.x*v0.x + v0.y*v0.y + v0.z*v0.z + v0.w*v0.w
             + v1.x*v1.x + v1.y*v1.y + v1.z*v1.z + v1.w*v1.w;
  us8 o;
  o[0]=f2bf(v0.x); o[1]=f2bf(v0.y); o[2]=f2bf(v0.z); o[3]=f2bf(v0.w);
  o[4]=f2bf(v1.x); o[5]=f2bf(v1.y); o[6]=f2bf(v1.z); o[7]=f2bf(v1.w);

  const int bc = row >> 7, m = (row >> 4) & 7, r = row & 15;
  const int kt = lane >> 2, slot = lane & 3;
  size_t off = ((size_t)(bc * 16 + kt)) * 4096 + m * 512 + slot * 128 + r * 8;
  *reinterpret_cast<us8*>(mub + off) = o;

  const float* sr = sd + (size_t)row * DD + lane * 8;
  float4 s0 = *reinterpret_cast<const float4*>(sr);
  float4 s1 = *reinterpret_cast<const float4*>(sr + 4);
  float ssum = s0.x + s0.y + s0.z + s0.w + s1.x + s1.y + s1.z + s1.w;
  float ssq  = s0.x*s0.x + s0.y*s0.y + s0.z*s0.z + s0.w*s0.w
             + s1.x*s1.x + s1.y*s1.y + s1.z*s1.z + s1.w*s1.w;
  #pragma unroll
  for (int offs = 32; offs; offs >>= 1) {
    musq += __shfl_xor(musq, offs, 64);
    ssum += __shfl_xor(ssum, offs, 64);
    ssq  += __shfl_xor(ssq,  offs, 64);
  }
  if (lane == 0) {
    float idn = 1.0f / (2.0f * ssq + 1e-8f);
    inv_denom[row] = idn;
    beta[row] = musq * idn + logf(ssum) + 0.91893853320467274f; // + 0.5*log(2pi)
  }
}

// ---- Kernel 3: 256x256 tile, BK=32, 4 LDS buffers, depth-3 counted-vmcnt ----
// out[n][k] = (2*dot - x_sq[n]) * inv_denom[k] - beta[k]
__global__ __launch_bounds__(512, 2) void gemm_eval(const ushort_t* __restrict__ xb,
                                                    const ushort_t* __restrict__ mub,
                                                    const float* __restrict__ x_sq,
                                                    const float* __restrict__ inv_denom,
                                                    const float* __restrict__ beta,
                                                    float* __restrict__ out) {
  // per buffer (32KB): A-half0 | A-half1 | B-half0 | B-half1, 4096 elems each
  __shared__ __align__(16) ushort_t lds[4][16384];   // 128 KiB

  const int t0 = threadIdx.x;
  const int lane = t0 & 63;
  const int w = t0 >> 6;
  const int wrow = w >> 2;   // 0..1  (128-row half)
  const int wcol = w & 3;    // 0..3  (64-col quarter)

  // bijective XCD swizzle (grid 512, 512 % 8 == 0)
  const int bid = blockIdx.x;
  const int swz = (bid & 7) * 64 + (bid >> 3);
  const int bm = swz >> 3, bn = swz & 7;

  const ushort_t* Aimg0 = xb  + ((size_t)(bm * 2 + 0) * 16) * 4096;
  const ushort_t* Aimg1 = xb  + ((size_t)(bm * 2 + 1) * 16) * 4096;
  const ushort_t* Bimg0 = mub + ((size_t)(bn * 2 + 0) * 16) * 4096;
  const ushort_t* Bimg1 = mub + ((size_t)(bn * 2 + 1) * 16) * 4096;

  f32x4 acc[8][4];
  #pragma unroll
  for (int mm = 0; mm < 8; ++mm)
    #pragma unroll
    for (int cc = 0; cc < 4; ++cc)
      acc[mm][cc] = (f32x4){0.f, 0.f, 0.f, 0.f};

#define ISSUE_A(kt_, buf_) do {                                                                   \
    __builtin_amdgcn_global_load_lds(AS1(Aimg0 + (size_t)(kt_) * 4096 + t0 * 8),                  \
                                     AS3(&lds[buf_][0] + t0 * 8), 16, 0, 0);                      \
    __builtin_amdgcn_global_load_lds(AS1(Aimg1 + (size_t)(kt_) * 4096 + t0 * 8),                  \
                                     AS3(&lds[buf_][4096] + t0 * 8), 16, 0, 0);                   \
  } while (0)
#define ISSUE_B(kt_, buf_) do {                                                                   \
    __builtin_amdgcn_global_load_lds(AS1(Bimg0 + (size_t)(kt_) * 4096 + t0 * 8),                  \
                                     AS3(&lds[buf_][8192] + t0 * 8), 16, 0, 0);                   \
    __builtin_amdgcn_global_load_lds(AS1(Bimg1 + (size_t)(kt_) * 4096 + t0 * 8),                  \
                                     AS3(&lds[buf_][12288] + t0 * 8), 16, 0, 0);                  \
  } while (0)

// One K-tile: 2 phases x 16 MFMA; staging of tile t+3 interleaved; counted wait.
// Hazard proof: tile t+3 writes buf (t-1)&3; all reads of tile t-1 were consumed
// by its MFMAs (lgkmcnt) before its post-MFMA barrier, which precedes any issue here.
#define TILE_BODY(t_, doIssue_, WAITASM) do {                                                     \
    const int buf_ = (t_) & 3;                                                                    \
    const ushort_t* Ab_ = &lds[buf_][wrow * 4096];                                                \
    const ushort_t* Bb_ = &lds[buf_][8192 + (wcol >> 1) * 4096 + (wcol & 1) * 2048];              \
    bf16x8 af_[4], bf_[4];                                                                        \
    _Pragma("unroll") for (int i = 0; i < 4; ++i)                                                 \
      af_[i] = *reinterpret_cast<const bf16x8*>(Ab_ + i * 512 + lane * 8);                        \
    _Pragma("unroll") for (int c = 0; c < 4; ++c)                                                 \
      bf_[c] = *reinterpret_cast<const bf16x8*>(Bb_ + c * 512 + lane * 8);                        \
    if (doIssue_) ISSUE_A((t_) + 3, ((t_) + 3) & 3);                                              \
    SBAR();                                                                                       \
    __builtin_amdgcn_s_setprio(1);                                                                \
    _Pragma("unroll") for (int i = 0; i < 4; ++i)                                                 \
      _Pragma("unroll") for (int c = 0; c < 4; ++c)                                               \
        acc[i][c] = __builtin_amdgcn_mfma_f32_16x16x32_bf16(af_[i], bf_[c], acc[i][c], 0, 0, 0);  \
    __builtin_amdgcn_s_setprio(0);                                                                \
    SBAR();                                                                                       \
    _Pragma("unroll") for (int i = 0; i < 4; ++i)                                                 \
      af_[i] = *reinterpret_cast<const bf16x8*>(Ab_ + (4 + i) * 512 + lane * 8);                  \
    if (doIssue_) ISSUE_B((t_) + 3, ((t_) + 3) & 3);                                              \
    SBAR();                                                                                       \
    __builtin_amdgcn_s_setprio(1);                                                                \
    _Pragma("unroll") for (int i = 0; i < 4; ++i)                                                 \
      _Pragma("unroll") for (int c = 0; c < 4; ++c)                                               \
        acc[4 + i][c] = __builtin_amdgcn_mfma_f32_16x16x32_bf16(af_[i], bf_[c], acc[4 + i][c], 0, 0, 0); \
    __builtin_amdgcn_s_setprio(0);                                                                \
    WAITASM;                                                                                      \
    SBAR();                                                                                       \
  } while (0)

  // prologue: stage tiles 0,1,2 (12 loads in flight), wait tile 0 only
  ISSUE_A(0, 0); ISSUE_B(0, 0);
  ISSUE_A(1, 1); ISSUE_B(1, 1);
  ISSUE_A(2, 2); ISSUE_B(2, 2);
  asm volatile("s_waitcnt vmcnt(8)" ::: "memory");
  SBAR();

  for (int t = 0; t < 13; ++t)
    TILE_BODY(t, 1, asm volatile("s_waitcnt vmcnt(8)" ::: "memory"));
  TILE_BODY(13, 0, asm volatile("s_waitcnt vmcnt(4)" ::: "memory"));
  TILE_BODY(14, 0, asm volatile("s_waitcnt vmcnt(0)" ::: "memory"));
  TILE_BODY(15, 0, (void)0);

#undef TILE_BODY
#undef ISSUE_A
#undef ISSUE_B

  // epilogue: C/D layout col=lane&15, row=(lane>>4)*4+reg  [verified passing]
  const int rl = lane & 15, rh = lane >> 4;
  const int colbase = bn * 256 + wcol * 64;
  float inv[4], bet[4];
  #pragma unroll
  for (int cc = 0; cc < 4; ++cc) {
    inv[cc] = inv_denom[colbase + cc * 16 + rl];
    bet[cc] = beta[colbase + cc * 16 + rl];
  }
  #pragma unroll
  for (int mm = 0; mm < 8; ++mm) {
    const int nb = bm * 256 + wrow * 128 + mm * 16 + rh * 4;
    #pragma unroll
    for (int reg = 0; reg < 4; ++reg) {
      const int n = nb + reg;
      const float xs = x_sq[n];
      float* op = out + (size_t)n * KK + colbase;
      #pragma unroll
      for (int cc = 0; cc < 4; ++cc)
        op[cc * 16 + rl] = (2.0f * acc[mm][cc][reg] - xs) * inv[cc] - bet[cc];
    }
  }
}

extern "C" void kernel_launch(void* const* d_in, const int* in_sizes, int n_in,
                              void* d_out, int out_size, void* d_ws, size_t ws_size,
                              hipStream_t stream) {
  const float* x   = (const float*)d_in[0];
  const float* mu  = (const float*)d_in[1];
  const float* sd  = (const float*)d_in[2];
  float* out = (float*)d_out;

  char* ws = (char*)d_ws;
  ushort_t* xb        = (ushort_t*)(ws);                    // N*D*2 = 16777216 B
  ushort_t* mub       = (ushort_t*)(ws + 16777216);         // K*D*2 =  2097152 B
  float*    x_sq      = (float*)(ws + 18874368);            // N*4
  float*    inv_denom = (float*)(ws + 18939904);            // K*4
  float*    beta      = (float*)(ws + 18948096);            // K*4

  prep_x<<<NN / 4, 256, 0, stream>>>(x, xb, x_sq);
  prep_mu<<<KK / 4, 256, 0, stream>>>(mu, sd, mub, inv_denom, beta);
  gemm_eval<<<(NN / 256) * (KK / 256), 512, 0, stream>>>(xb, mub, x_sq, inv_denom, beta, out);
}

// Round 4
// 192.130 us; speedup vs baseline: 1.0527x; 1.0372x over previous
//
#include <hip/hip_runtime.h>
#include <hip/hip_bf16.h>
#include <stdint.h>

// Problem constants: N=16384, K=2048, D=512
#define NN 16384
#define KK 2048
#define DD 512

typedef __bf16 bf16x8 __attribute__((ext_vector_type(8)));
typedef float f32x4 __attribute__((ext_vector_type(4)));
typedef unsigned short ushort_t;
typedef ushort_t us8 __attribute__((ext_vector_type(8)));

#define AS1(p) ((const __attribute__((address_space(1))) void*)(p))
#define AS3(p) ((__attribute__((address_space(3))) void*)(p))
#define FENCE() asm volatile("" ::: "memory")
#define SBAR()  do { FENCE(); __builtin_amdgcn_s_barrier(); FENCE(); } while (0)

__device__ inline ushort_t f2bf(float f) {
  uint32_t u = __float_as_uint(f);
  u += 0x7fffu + ((u >> 16) & 1u);   // RNE
  return (ushort_t)(u >> 16);
}

// ---------------------------------------------------------------------------
// Packed fragment-major images (unchanged from round 3 — verified passing).
// One image = 128 rows x 32 k = 4096 bf16 = 8KB:
//   elem(row = m*16 + r, k = slot*8 + j) -> m*512 + slot*128 + r*8 + j
//   read side: frag addr = m*512 + lane*8  (lane = slot*16 + r) -> lane-linear
//   ds_read_b128, 2 lanes/bank = conflict-free; staging is a linear 8KB copy.
// xb image id  = (br*16 + kt), br = row>>7 (128 row-blocks), kt = k>>5 (16)
// mub image id = (bc*16 + kt), bc = col>>7 (16 col-blocks)
// ---------------------------------------------------------------------------

// ---- Kernel 1: x -> packed bf16 images + x_sq[n] ----
__global__ __launch_bounds__(256) void prep_x(const float* __restrict__ x,
                                              ushort_t* __restrict__ xb,
                                              float* __restrict__ x_sq) {
  const int wave = threadIdx.x >> 6;
  const int lane = threadIdx.x & 63;
  const int row = blockIdx.x * 4 + wave;
  const float* xr = x + (size_t)row * DD + lane * 8;
  float4 v0 = *reinterpret_cast<const float4*>(xr);
  float4 v1 = *reinterpret_cast<const float4*>(xr + 4);
  float s = v0.x*v0.x + v0.y*v0.y + v0.z*v0.z + v0.w*v0.w
          + v1.x*v1.x + v1.y*v1.y + v1.z*v1.z + v1.w*v1.w;
  us8 o;
  o[0]=f2bf(v0.x); o[1]=f2bf(v0.y); o[2]=f2bf(v0.z); o[3]=f2bf(v0.w);
  o[4]=f2bf(v1.x); o[5]=f2bf(v1.y); o[6]=f2bf(v1.z); o[7]=f2bf(v1.w);

  const int br = row >> 7, m = (row >> 4) & 7, r = row & 15;
  const int kt = lane >> 2, slot = lane & 3;
  size_t off = ((size_t)(br * 16 + kt)) * 4096 + m * 512 + slot * 128 + r * 8;
  *reinterpret_cast<us8*>(xb + off) = o;

  #pragma unroll
  for (int offs = 32; offs; offs >>= 1) s += __shfl_xor(s, offs, 64);
  if (lane == 0) x_sq[row] = s;
}

// ---- Kernel 2: mu -> packed bf16 images + per-k constants ----
__global__ __launch_bounds__(256) void prep_mu(const float* __restrict__ mu,
                                               const float* __restrict__ sd,
                                               ushort_t* __restrict__ mub,
                                               float* __restrict__ inv_denom,
                                               float* __restrict__ beta) {
  const int wave = threadIdx.x >> 6;
  const int lane = threadIdx.x & 63;
  const int row = blockIdx.x * 4 + wave;
  const float* mr = mu + (size_t)row * DD + lane * 8;
  float4 v0 = *reinterpret_cast<const float4*>(mr);
  float4 v1 = *reinterpret_cast<const float4*>(mr + 4);
  float musq = v0.x*v0.x + v0.y*v0.y + v0.z*v0.z + v0.w*v0.w
             + v1.x*v1.x + v1.y*v1.y + v1.z*v1.z + v1.w*v1.w;
  us8 o;
  o[0]=f2bf(v0.x); o[1]=f2bf(v0.y); o[2]=f2bf(v0.z); o[3]=f2bf(v0.w);
  o[4]=f2bf(v1.x); o[5]=f2bf(v1.y); o[6]=f2bf(v1.z); o[7]=f2bf(v1.w);

  const int bc = row >> 7, m = (row >> 4) & 7, r = row & 15;
  const int kt = lane >> 2, slot = lane & 3;
  size_t off = ((size_t)(bc * 16 + kt)) * 4096 + m * 512 + slot * 128 + r * 8;
  *reinterpret_cast<us8*>(mub + off) = o;

  const float* sr = sd + (size_t)row * DD + lane * 8;
  float4 s0 = *reinterpret_cast<const float4*>(sr);
  float4 s1 = *reinterpret_cast<const float4*>(sr + 4);
  float ssum = s0.x + s0.y + s0.z + s0.w + s1.x + s1.y + s1.z + s1.w;
  float ssq  = s0.x*s0.x + s0.y*s0.y + s0.z*s0.z + s0.w*s0.w
             + s1.x*s1.x + s1.y*s1.y + s1.z*s1.z + s1.w*s1.w;
  #pragma unroll
  for (int offs = 32; offs; offs >>= 1) {
    musq += __shfl_xor(musq, offs, 64);
    ssum += __shfl_xor(ssum, offs, 64);
    ssq  += __shfl_xor(ssq,  offs, 64);
  }
  if (lane == 0) {
    float idn = 1.0f / (2.0f * ssq + 1e-8f);
    inv_denom[row] = idn;
    beta[row] = musq * idn + logf(ssum) + 0.91893853320467274f; // + 0.5*log(2pi)
  }
}

// ---- Kernel 3: 128x128 tile, BK=32, 3 LDS buffers (48KB -> 3 blocks/CU),
//      depth-2 counted vmcnt, wait BEFORE the per-tile barrier ----
// out[n][k] = (2*dot - x_sq[n]) * inv_denom[k] - beta[k]
__global__ __launch_bounds__(256, 3) void gemm_eval(const ushort_t* __restrict__ xb,
                                                    const ushort_t* __restrict__ mub,
                                                    const float* __restrict__ x_sq,
                                                    const float* __restrict__ inv_denom,
                                                    const float* __restrict__ beta,
                                                    float* __restrict__ out) {
  // buffer = A image (4096 elems) | B image (4096 elems) = 16KB; 3 buffers
  __shared__ __align__(16) ushort_t lds[3][8192];   // 48 KiB

  const int t0 = threadIdx.x;
  const int lane = t0 & 63;
  const int w = t0 >> 6;          // 4 waves, 2x2 grid; each wave 64x64 output
  const int wrow = w >> 1;
  const int wcol = w & 1;

  // bijective XCD swizzle (grid 2048, 2048 % 8 == 0)
  const int bid = blockIdx.x;
  const int swz = (bid & 7) * 256 + (bid >> 3);
  const int bm = swz >> 4, bn = swz & 15;    // XCD x: bm in [x*16, x*16+15], all bn

  const ushort_t* Aimg = xb  + (size_t)(bm * 16) * 4096;
  const ushort_t* Bimg = mub + (size_t)(bn * 16) * 4096;

  f32x4 acc[4][4];
  #pragma unroll
  for (int m = 0; m < 4; ++m)
    #pragma unroll
    for (int c = 0; c < 4; ++c)
      acc[m][c] = (f32x4){0.f, 0.f, 0.f, 0.f};

  // one stage = 4 x global_load_lds(16B)/thread: A 8KB + B 8KB, linear copies
#define ISSUE(kt_) do {                                                                  \
    const int b_ = (kt_) % 3;                                                            \
    const ushort_t* a_ = Aimg + (size_t)(kt_) * 4096;                                    \
    const ushort_t* bsrc_ = Bimg + (size_t)(kt_) * 4096;                                 \
    __builtin_amdgcn_global_load_lds(AS1(a_ + t0 * 8),                                   \
                                     AS3(&lds[b_][0] + t0 * 8), 16, 0, 0);               \
    __builtin_amdgcn_global_load_lds(AS1(a_ + (t0 + 256) * 8),                           \
                                     AS3(&lds[b_][0] + (t0 + 256) * 8), 16, 0, 0);       \
    __builtin_amdgcn_global_load_lds(AS1(bsrc_ + t0 * 8),                                \
                                     AS3(&lds[b_][4096] + t0 * 8), 16, 0, 0);            \
    __builtin_amdgcn_global_load_lds(AS1(bsrc_ + (t0 + 256) * 8),                        \
                                     AS3(&lds[b_][4096] + (t0 + 256) * 8), 16, 0, 0);    \
  } while (0)

  // Per-tile body. Hazards:
  //  - read buf[t]: all waves' stage(t) loads completed before SBAR at end of
  //    tile t-1 (the vmcnt there keeps only stage(t+1) in flight) -> safe.
  //  - ISSUE(t+2) writes buf[(t+2)%3] = buf[(t-1)%3]; tile t-1's reads were
  //    consumed (lgkmcnt before its MFMAs) before SBAR(t-1->t) -> safe.
#define TILE(t_, doIssue_, WAITASM) do {                                                 \
    const ushort_t* Ab_ = &lds[(t_) % 3][0];                                             \
    const ushort_t* Bb_ = &lds[(t_) % 3][4096];                                          \
    bf16x8 af_[4], bf_[4];                                                               \
    _Pragma("unroll") for (int m = 0; m < 4; ++m)                                        \
      af_[m] = *reinterpret_cast<const bf16x8*>(Ab_ + (wrow * 4 + m) * 512 + lane * 8);  \
    _Pragma("unroll") for (int c = 0; c < 4; ++c)                                        \
      bf_[c] = *reinterpret_cast<const bf16x8*>(Bb_ + (wcol * 4 + c) * 512 + lane * 8);  \
    if (doIssue_) ISSUE((t_) + 2);                                                       \
    __builtin_amdgcn_s_setprio(1);                                                       \
    _Pragma("unroll") for (int m = 0; m < 4; ++m)                                        \
      _Pragma("unroll") for (int c = 0; c < 4; ++c)                                      \
        acc[m][c] = __builtin_amdgcn_mfma_f32_16x16x32_bf16(af_[m], bf_[c],              \
                                                            acc[m][c], 0, 0, 0);         \
    __builtin_amdgcn_s_setprio(0);                                                       \
    WAITASM;                                                                             \
    SBAR();                                                                              \
  } while (0)

  // prologue: stage tiles 0,1 (8 loads); ensure tile 0 resident for everyone
  ISSUE(0); ISSUE(1);
  asm volatile("s_waitcnt vmcnt(4)" ::: "memory");
  SBAR();

  #pragma unroll
  for (int t = 0; t < 14; ++t)
    TILE(t, 1, asm volatile("s_waitcnt vmcnt(4)" ::: "memory"));
  TILE(14, 0, asm volatile("s_waitcnt vmcnt(0)" ::: "memory"));
  {  // tile 15: no issue, no wait needed after
    const ushort_t* Ab_ = &lds[15 % 3][0];
    const ushort_t* Bb_ = &lds[15 % 3][4096];
    bf16x8 af_[4], bf_[4];
    #pragma unroll
    for (int m = 0; m < 4; ++m)
      af_[m] = *reinterpret_cast<const bf16x8*>(Ab_ + (wrow * 4 + m) * 512 + lane * 8);
    #pragma unroll
    for (int c = 0; c < 4; ++c)
      bf_[c] = *reinterpret_cast<const bf16x8*>(Bb_ + (wcol * 4 + c) * 512 + lane * 8);
    #pragma unroll
    for (int m = 0; m < 4; ++m)
      #pragma unroll
      for (int c = 0; c < 4; ++c)
        acc[m][c] = __builtin_amdgcn_mfma_f32_16x16x32_bf16(af_[m], bf_[c],
                                                            acc[m][c], 0, 0, 0);
  }
#undef TILE
#undef ISSUE

  // epilogue: C/D layout col=lane&15, row=(lane>>4)*4+reg  [verified passing]
  const int rl = lane & 15, rh = lane >> 4;
  const int colbase = bn * 128 + wcol * 64;
  float inv[4], bet[4];
  #pragma unroll
  for (int c = 0; c < 4; ++c) {
    inv[c] = inv_denom[colbase + c * 16 + rl];
    bet[c] = beta[colbase + c * 16 + rl];
  }
  #pragma unroll
  for (int m = 0; m < 4; ++m) {
    const int nb = bm * 128 + wrow * 64 + m * 16 + rh * 4;
    #pragma unroll
    for (int reg = 0; reg < 4; ++reg) {
      const int n = nb + reg;
      const float xs = x_sq[n];
      float* op = out + (size_t)n * KK + colbase;
      #pragma unroll
      for (int c = 0; c < 4; ++c)
        op[c * 16 + rl] = (2.0f * acc[m][c][reg] - xs) * inv[c] - bet[c];
    }
  }
}

extern "C" void kernel_launch(void* const* d_in, const int* in_sizes, int n_in,
                              void* d_out, int out_size, void* d_ws, size_t ws_size,
                              hipStream_t stream) {
  const float* x   = (const float*)d_in[0];
  const float* mu  = (const float*)d_in[1];
  const float* sd  = (const float*)d_in[2];
  float* out = (float*)d_out;

  char* ws = (char*)d_ws;
  ushort_t* xb        = (ushort_t*)(ws);                    // N*D*2 = 16777216 B
  ushort_t* mub       = (ushort_t*)(ws + 16777216);         // K*D*2 =  2097152 B
  float*    x_sq      = (float*)(ws + 18874368);            // N*4
  float*    inv_denom = (float*)(ws + 18939904);            // K*4
  float*    beta      = (float*)(ws + 18948096);            // K*4

  prep_mu<<<KK / 4, 256, 0, stream>>>(mu, sd, mub, inv_denom, beta);
  prep_x<<<NN / 4, 256, 0, stream>>>(x, xb, x_sq);
  gemm_eval<<<(NN / 128) * (KK / 128), 256, 0, stream>>>(xb, mub, x_sq, inv_denom, beta, out);
}